// Round 1
// baseline (633.636 us; speedup 1.0000x reference)
//
#include <hip/hip_runtime.h>
#include <math.h>

#define N_NODES 100000
#define N_EDGES 1600000
#define EPSF 1e-12f
#define CHUNK 1024
#define NCHUNKS ((N_NODES + CHUNK - 1) / CHUNK)   // 98

// ---------------- helpers ----------------
__device__ __forceinline__ float wred64(float v) {
    // full 64-lane butterfly reduce; result valid in all lanes
    #pragma unroll
    for (int m = 32; m >= 1; m >>= 1) v += __shfl_xor(v, m, 64);
    return v;
}

// ---------------- kernel 1: per-edge |ea|^2 + degree histogram ----------------
__global__ void prep_edges(const float* __restrict__ ea, const int* __restrict__ col,
                           float* __restrict__ sqea, int* __restrict__ cnt) {
    int e = blockIdx.x * blockDim.x + threadIdx.x;
    if (e >= N_EDGES) return;
    const float4* p = (const float4*)(ea + (size_t)e * 16);
    float4 a = p[0], b = p[1], c = p[2], d = p[3];
    float s = a.x*a.x + a.y*a.y + a.z*a.z + a.w*a.w
            + b.x*b.x + b.y*b.y + b.z*b.z + b.w*b.w
            + c.x*c.x + c.y*c.y + c.z*c.z + c.w*c.w
            + d.x*d.x + d.y*d.y + d.z*d.z + d.w*d.w;
    sqea[e] = s;
    atomicAdd(&cnt[col[e]], 1);
}

// ---------------- kernel 2: per-node |x|^2 ----------------
__global__ void node_sq(const float* __restrict__ x, float* __restrict__ nx) {
    int v = blockIdx.x * blockDim.x + threadIdx.x;
    if (v >= N_NODES) return;
    const float4* p = (const float4*)(x + (size_t)v * 128);
    float s = 0.f;
    #pragma unroll
    for (int i = 0; i < 32; ++i) {
        float4 t = p[i];
        s += t.x*t.x + t.y*t.y + t.z*t.z + t.w*t.w;
    }
    nx[v] = s;
}

// ---------------- scan (3 kernels) ----------------
__global__ void scan_part(const int* __restrict__ cnt, int* __restrict__ psum) {
    __shared__ int sd[CHUNK];
    int i = blockIdx.x * CHUNK + threadIdx.x;
    sd[threadIdx.x] = (i < N_NODES) ? cnt[i] : 0;
    __syncthreads();
    for (int s = CHUNK / 2; s > 0; s >>= 1) {
        if (threadIdx.x < s) sd[threadIdx.x] += sd[threadIdx.x + s];
        __syncthreads();
    }
    if (threadIdx.x == 0) psum[blockIdx.x] = sd[0];
}

__global__ void scan_top(const int* __restrict__ psum, int* __restrict__ coff,
                         int* __restrict__ off) {
    if (blockIdx.x == 0 && threadIdx.x == 0) {
        int run = 0;
        for (int i = 0; i < NCHUNKS; ++i) { coff[i] = run; run += psum[i]; }
        off[N_NODES] = N_EDGES;
    }
}

__global__ void scan_apply(const int* __restrict__ cnt, const int* __restrict__ coff,
                           int* __restrict__ off, int* __restrict__ head) {
    __shared__ int sd[CHUNK];
    int i = blockIdx.x * CHUNK + threadIdx.x;
    int v = (i < N_NODES) ? cnt[i] : 0;
    sd[threadIdx.x] = v;
    __syncthreads();
    // Hillis-Steele inclusive scan
    for (int s = 1; s < CHUNK; s <<= 1) {
        int t = (threadIdx.x >= s) ? sd[threadIdx.x - s] : 0;
        __syncthreads();
        sd[threadIdx.x] += t;
        __syncthreads();
    }
    if (i < N_NODES) {
        int excl = coff[blockIdx.x] + sd[threadIdx.x] - v;
        off[i] = excl;
        head[i] = excl;
    }
}

// ---------------- kernel: scatter edges into CSR-by-col ----------------
__global__ void scatter_e(const int* __restrict__ row, const int* __restrict__ col,
                          int* __restrict__ head, int* __restrict__ srow,
                          int* __restrict__ seid) {
    int e = blockIdx.x * blockDim.x + threadIdx.x;
    if (e >= N_EDGES) return;
    int c = col[e];
    int p = atomicAdd(&head[c], 1);
    srow[p] = row[e];
    seid[p] = e;
}

// ---------------- kernel: y1 = x @ W1[0:128,:]  (f32 tiled GEMM) ----------------
__global__ __launch_bounds__(256) void gemm_y1(const float* __restrict__ x,
                                               const float* __restrict__ W1,
                                               float* __restrict__ y1) {
    __shared__ float xs[64][129];            // +1 pad breaks bank aliasing
    int r0 = blockIdx.x * 64;
    int t = threadIdx.x;
    for (int i = t; i < 64 * 32; i += 256) { // 64 rows x 32 float4
        int rr = i >> 5, c4 = (i & 31) * 4;
        int gr = r0 + rr;
        float4 v = (gr < N_NODES) ? *(const float4*)(x + (size_t)gr * 128 + c4)
                                  : make_float4(0.f, 0.f, 0.f, 0.f);
        xs[rr][c4] = v.x; xs[rr][c4 + 1] = v.y; xs[rr][c4 + 2] = v.z; xs[rr][c4 + 3] = v.w;
    }
    __syncthreads();
    int tx = t & 31, ty = t >> 5;            // 32 col-groups x 8 row-groups
    float4 acc[8];
    #pragma unroll
    for (int i = 0; i < 8; ++i) acc[i] = make_float4(0.f, 0.f, 0.f, 0.f);
    for (int k = 0; k < 128; ++k) {
        float4 wv = *(const float4*)(W1 + (size_t)k * 128 + tx * 4);
        #pragma unroll
        for (int i = 0; i < 8; ++i) {
            float xv = xs[ty * 8 + i][k];
            acc[i].x += xv * wv.x; acc[i].y += xv * wv.y;
            acc[i].z += xv * wv.z; acc[i].w += xv * wv.w;
        }
    }
    #pragma unroll
    for (int i = 0; i < 8; ++i) {
        int rr = r0 + ty * 8 + i;
        if (rr < N_NODES) *(float4*)(y1 + (size_t)rr * 128 + tx * 4) = acc[i];
    }
}

// ---------------- kernel: layer-1 aggregate + linear + norm + relu + fused yh/nh ---
__global__ __launch_bounds__(256) void layer1(
        const float* __restrict__ y1, const float* __restrict__ ea,
        const float* __restrict__ nx, const float* __restrict__ sqea,
        const int* __restrict__ off, const int* __restrict__ srow,
        const int* __restrict__ seid,
        const float* __restrict__ W1, const float* __restrict__ b1,
        const float* __restrict__ W2,
        float* __restrict__ yh, float* __restrict__ nh) {
    int wid = (blockIdx.x << 2) | (threadIdx.x >> 6);  // wave per node
    int lane = threadIdx.x & 63;
    if (wid >= N_NODES) return;
    int s = off[wid], e = off[wid + 1];
    float a0 = 0.f, a1 = 0.f, ae = 0.f;
    for (int t = s; t < e; ++t) {
        int r = srow[t], id = seid[t];
        float w = 1.0f / fmaxf(sqrtf(nx[r] + sqea[id]), EPSF);
        a0 += y1[(size_t)r * 128 + lane] * w;
        a1 += y1[(size_t)r * 128 + 64 + lane] * w;
        if (lane < 16) ae += ea[(size_t)id * 16 + lane] * w;
    }
    float ic = 1.0f / fmaxf((float)(e - s), 1.0f);
    float o0 = a0 * ic + b1[lane];
    float o1 = a1 * ic + b1[64 + lane];
    ae *= ic;
    #pragma unroll
    for (int k = 0; k < 16; ++k) {           // edge-feature part: (sea) @ W1[128:144,:]
        float sk = __shfl(ae, k, 64);
        o0 += sk * W1[(size_t)(128 + k) * 128 + lane];
        o1 += sk * W1[(size_t)(128 + k) * 128 + 64 + lane];
    }
    float ss = wred64(o0 * o0 + o1 * o1);
    float inv = 1.0f / fmaxf(sqrtf(ss), EPSF);
    float h0 = fmaxf(o0 * inv, 0.f);         // normalize + relu
    float h1 = fmaxf(o1 * inv, 0.f);
    float nhv = wred64(h0 * h0 + h1 * h1);   // |relu(h)|^2 for layer-2 norms
    // yh = relu(h) @ W2[0:128,:]  (4 outputs, wave reduce) — h never stored
    float4 wa = *(const float4*)(W2 + (size_t)lane * 4);
    float4 wb = *(const float4*)(W2 + (size_t)(lane + 64) * 4);
    float p0 = wred64(h0 * wa.x + h1 * wb.x);
    float p1 = wred64(h0 * wa.y + h1 * wb.y);
    float p2 = wred64(h0 * wa.z + h1 * wb.z);
    float p3 = wred64(h0 * wa.w + h1 * wb.w);
    if (lane == 0) {
        *(float4*)(yh + (size_t)wid * 4) = make_float4(p0, p1, p2, p3);
        nh[wid] = nhv;
    }
}

// ---------------- kernel: layer-2 aggregate + linear + norm + sigmoid -------------
__global__ __launch_bounds__(256) void layer2(
        const float* __restrict__ yh, const float* __restrict__ ea,
        const float* __restrict__ nh, const float* __restrict__ sqea,
        const int* __restrict__ off, const int* __restrict__ srow,
        const int* __restrict__ seid,
        const float* __restrict__ W2, const float* __restrict__ b2,
        float* __restrict__ out) {
    int v = blockIdx.x * blockDim.x + threadIdx.x;   // thread per node
    if (v >= N_NODES) return;
    int s = off[v], e = off[v + 1];
    float ax = 0.f, ay = 0.f, az = 0.f, aw = 0.f;
    float4 se0 = make_float4(0,0,0,0), se1 = se0, se2 = se0, se3 = se0;
    for (int t = s; t < e; ++t) {
        int r = srow[t], id = seid[t];
        float w = 1.0f / fmaxf(sqrtf(nh[r] + sqea[id]), EPSF);
        float4 yv = *(const float4*)(yh + (size_t)r * 4);
        ax += yv.x * w; ay += yv.y * w; az += yv.z * w; aw += yv.w * w;
        const float4* ep = (const float4*)(ea + (size_t)id * 16);
        float4 e0 = ep[0], e1 = ep[1], e2 = ep[2], e3 = ep[3];
        se0.x += e0.x*w; se0.y += e0.y*w; se0.z += e0.z*w; se0.w += e0.w*w;
        se1.x += e1.x*w; se1.y += e1.y*w; se1.z += e1.z*w; se1.w += e1.w*w;
        se2.x += e2.x*w; se2.y += e2.y*w; se2.z += e2.z*w; se2.w += e2.w*w;
        se3.x += e3.x*w; se3.y += e3.y*w; se3.z += e3.z*w; se3.w += e3.w*w;
    }
    float ic = 1.0f / fmaxf((float)(e - s), 1.0f);
    float accv[4] = {ax, ay, az, aw};
    float sev[16] = {se0.x, se0.y, se0.z, se0.w, se1.x, se1.y, se1.z, se1.w,
                     se2.x, se2.y, se2.z, se2.w, se3.x, se3.y, se3.z, se3.w};
    float ov[4];
    #pragma unroll
    for (int j = 0; j < 4; ++j) {
        float o = accv[j] * ic + b2[j];
        #pragma unroll
        for (int k = 0; k < 16; ++k) o += sev[k] * ic * W2[(size_t)(128 + k) * 4 + j];
        ov[j] = o;
    }
    float ss = ov[0]*ov[0] + ov[1]*ov[1] + ov[2]*ov[2] + ov[3]*ov[3];
    float inv = 1.0f / fmaxf(sqrtf(ss), EPSF);
    float4 res;
    res.x = 1.0f / (1.0f + expf(-(ov[0] * inv)));
    res.y = 1.0f / (1.0f + expf(-(ov[1] * inv)));
    res.z = 1.0f / (1.0f + expf(-(ov[2] * inv)));
    res.w = 1.0f / (1.0f + expf(-(ov[3] * inv)));
    *(float4*)(out + (size_t)v * 4) = res;
}

// ---------------- launch ----------------
extern "C" void kernel_launch(void* const* d_in, const int* in_sizes, int n_in,
                              void* d_out, int out_size, void* d_ws, size_t ws_size,
                              hipStream_t stream) {
    const float* x   = (const float*)d_in[0];
    const int*   ei  = (const int*)d_in[1];
    const float* ea  = (const float*)d_in[2];
    const float* W1  = (const float*)d_in[3];
    const float* b1  = (const float*)d_in[4];
    const float* W2  = (const float*)d_in[5];
    const float* b2  = (const float*)d_in[6];
    const int* row = ei;
    const int* col = ei + N_EDGES;
    float* out = (float*)d_out;

    // workspace carve-up (256B aligned)
    char* ws = (char*)d_ws;
    size_t o = 0;
    auto carve = [&](size_t bytes) { char* p = ws + o; o = (o + bytes + 255) & ~(size_t)255; return p; };
    float* y1   = (float*)carve((size_t)N_NODES * 128 * 4);
    float* sqea = (float*)carve((size_t)N_EDGES * 4);
    int*   srow = (int*)carve((size_t)N_EDGES * 4);
    int*   seid = (int*)carve((size_t)N_EDGES * 4);
    int*   cnt  = (int*)carve((size_t)N_NODES * 4);
    int*   off  = (int*)carve((size_t)(N_NODES + 1) * 4);
    int*   head = (int*)carve((size_t)N_NODES * 4);
    float* nx   = (float*)carve((size_t)N_NODES * 4);
    float* nh   = (float*)carve((size_t)N_NODES * 4);
    float* yh   = (float*)carve((size_t)N_NODES * 4 * 4);
    int*   psum = (int*)carve((size_t)NCHUNKS * 4);
    int*   coff = (int*)carve((size_t)NCHUNKS * 4);
    (void)ws_size; (void)in_sizes; (void)n_in; (void)out_size;

    hipMemsetAsync(cnt, 0, (size_t)N_NODES * 4, stream);

    dim3 b256(256);
    prep_edges<<<(N_EDGES + 255) / 256, b256, 0, stream>>>(ea, col, sqea, cnt);
    node_sq<<<(N_NODES + 255) / 256, b256, 0, stream>>>(x, nx);
    gemm_y1<<<(N_NODES + 63) / 64, b256, 0, stream>>>(x, W1, y1);

    scan_part<<<NCHUNKS, CHUNK, 0, stream>>>(cnt, psum);
    scan_top<<<1, 64, 0, stream>>>(psum, coff, off);
    scan_apply<<<NCHUNKS, CHUNK, 0, stream>>>(cnt, coff, off, head);
    scatter_e<<<(N_EDGES + 255) / 256, b256, 0, stream>>>(row, col, head, srow, seid);

    layer1<<<(N_NODES + 3) / 4, b256, 0, stream>>>(y1, ea, nx, sqea, off, srow, seid,
                                                   W1, b1, W2, yh, nh);
    layer2<<<(N_NODES + 255) / 256, b256, 0, stream>>>(yh, ea, nh, sqea, off, srow, seid,
                                                       W2, b2, out);
}

// Round 2
// 501.331 us; speedup vs baseline: 1.2639x; 1.2639x over previous
//
#include <hip/hip_runtime.h>
#include <math.h>

#define N_NODES 100000
#define N_EDGES 1600000
#define CHUNK 1024
#define NCHUNKS ((N_NODES + CHUNK - 1) / CHUNK)   // 98

// ---------------- helpers ----------------
__device__ __forceinline__ float red32(float v) {
    // butterfly reduce within each 32-lane half; both halves get their own total
    #pragma unroll
    for (int m = 16; m >= 1; m >>= 1) v += __shfl_xor(v, m, 64);
    return v;
}

// ---------- kernel 1: per-edge |ea|^2, pea = ea@W2e, degree histogram ----------
__global__ __launch_bounds__(256) void prep_edges(
        const float* __restrict__ ea, const int* __restrict__ col,
        const float* __restrict__ W2,
        float* __restrict__ sqea, float4* __restrict__ pea, int* __restrict__ cnt) {
    __shared__ float w2e[64];                 // W2[128:144, 0:4]
    int t = threadIdx.x;
    if (t < 64) w2e[t] = W2[128 * 4 + t];
    __syncthreads();
    int e = blockIdx.x * 256 + t;
    if (e >= N_EDGES) return;
    const float4* p = (const float4*)(ea + (size_t)e * 16);
    float4 q0 = p[0], q1 = p[1], q2 = p[2], q3 = p[3];
    float a[16] = {q0.x,q0.y,q0.z,q0.w, q1.x,q1.y,q1.z,q1.w,
                   q2.x,q2.y,q2.z,q2.w, q3.x,q3.y,q3.z,q3.w};
    float s = 0.f;
    float4 pv = make_float4(0.f, 0.f, 0.f, 0.f);
    #pragma unroll
    for (int k = 0; k < 16; ++k) {
        s += a[k] * a[k];
        pv.x += a[k] * w2e[k * 4 + 0];
        pv.y += a[k] * w2e[k * 4 + 1];
        pv.z += a[k] * w2e[k * 4 + 2];
        pv.w += a[k] * w2e[k * 4 + 3];
    }
    sqea[e] = s;
    pea[e] = pv;
    atomicAdd(&cnt[col[e]], 1);
}

// ---------------- kernel 2: per-node |x|^2 ----------------
__global__ void node_sq(const float* __restrict__ x, float* __restrict__ nx) {
    int v = blockIdx.x * blockDim.x + threadIdx.x;
    if (v >= N_NODES) return;
    const float4* p = (const float4*)(x + (size_t)v * 128);
    float s = 0.f;
    #pragma unroll
    for (int i = 0; i < 32; ++i) {
        float4 t = p[i];
        s += t.x*t.x + t.y*t.y + t.z*t.z + t.w*t.w;
    }
    nx[v] = s;
}

// ---------------- scan (3 kernels) ----------------
__global__ void scan_part(const int* __restrict__ cnt, int* __restrict__ psum) {
    __shared__ int sd[CHUNK];
    int i = blockIdx.x * CHUNK + threadIdx.x;
    sd[threadIdx.x] = (i < N_NODES) ? cnt[i] : 0;
    __syncthreads();
    for (int s = CHUNK / 2; s > 0; s >>= 1) {
        if (threadIdx.x < s) sd[threadIdx.x] += sd[threadIdx.x + s];
        __syncthreads();
    }
    if (threadIdx.x == 0) psum[blockIdx.x] = sd[0];
}

__global__ void scan_top(const int* __restrict__ psum, int* __restrict__ coff,
                         int* __restrict__ off) {
    if (blockIdx.x == 0 && threadIdx.x == 0) {
        int run = 0;
        for (int i = 0; i < NCHUNKS; ++i) { coff[i] = run; run += psum[i]; }
        off[N_NODES] = N_EDGES;
    }
}

__global__ void scan_apply(const int* __restrict__ cnt, const int* __restrict__ coff,
                           int* __restrict__ off, int* __restrict__ head) {
    __shared__ int sd[CHUNK];
    int i = blockIdx.x * CHUNK + threadIdx.x;
    int v = (i < N_NODES) ? cnt[i] : 0;
    sd[threadIdx.x] = v;
    __syncthreads();
    for (int s = 1; s < CHUNK; s <<= 1) {
        int t = (threadIdx.x >= s) ? sd[threadIdx.x - s] : 0;
        __syncthreads();
        sd[threadIdx.x] += t;
        __syncthreads();
    }
    if (i < N_NODES) {
        int excl = coff[blockIdx.x] + sd[threadIdx.x] - v;
        off[i] = excl;
        head[i] = excl;
    }
}

// ---- scatter edges into CSR-by-col; fold layer-1 weight w1 into the slot ----
__global__ __launch_bounds__(256) void scatter_e(
        const int* __restrict__ row, const int* __restrict__ col,
        const float* __restrict__ nx, const float* __restrict__ sqea,
        int* __restrict__ head, float2* __restrict__ csr_rw,
        int* __restrict__ seid, int* __restrict__ epos) {
    int e = blockIdx.x * blockDim.x + threadIdx.x;
    if (e >= N_EDGES) return;
    int c = col[e];
    int r = row[e];
    float w1 = rsqrtf(fmaxf(nx[r] + sqea[e], 1e-24f));  // == 1/max(sqrt(s),1e-12)
    int p = atomicAdd(&head[c], 1);
    float2 rw; rw.x = __int_as_float(r); rw.y = w1;
    csr_rw[p] = rw;
    seid[p] = e;
    epos[e] = p;
}

// ---------------- kernel: y1 = x @ W1[0:128,:]  (f32 tiled GEMM) ----------------
__global__ __launch_bounds__(256) void gemm_y1(const float* __restrict__ x,
                                               const float* __restrict__ W1,
                                               float* __restrict__ y1) {
    __shared__ float xs[64][129];
    int r0 = blockIdx.x * 64;
    int t = threadIdx.x;
    for (int i = t; i < 64 * 32; i += 256) {
        int rr = i >> 5, c4 = (i & 31) * 4;
        int gr = r0 + rr;
        float4 v = (gr < N_NODES) ? *(const float4*)(x + (size_t)gr * 128 + c4)
                                  : make_float4(0.f, 0.f, 0.f, 0.f);
        xs[rr][c4] = v.x; xs[rr][c4 + 1] = v.y; xs[rr][c4 + 2] = v.z; xs[rr][c4 + 3] = v.w;
    }
    __syncthreads();
    int tx = t & 31, ty = t >> 5;
    float4 acc[8];
    #pragma unroll
    for (int i = 0; i < 8; ++i) acc[i] = make_float4(0.f, 0.f, 0.f, 0.f);
    for (int k = 0; k < 128; ++k) {
        float4 wv = *(const float4*)(W1 + (size_t)k * 128 + tx * 4);
        #pragma unroll
        for (int i = 0; i < 8; ++i) {
            float xv = xs[ty * 8 + i][k];
            acc[i].x += xv * wv.x; acc[i].y += xv * wv.y;
            acc[i].z += xv * wv.z; acc[i].w += xv * wv.w;
        }
    }
    #pragma unroll
    for (int i = 0; i < 8; ++i) {
        int rr = r0 + ty * 8 + i;
        if (rr < N_NODES) *(float4*)(y1 + (size_t)rr * 128 + tx * 4) = acc[i];
    }
}

// ---- layer-1: wave/node, 2 edges per iter (float4 lanes), fused epilogue ----
__global__ __launch_bounds__(256) void layer1(
        const float* __restrict__ y1, const float* __restrict__ ea,
        const float2* __restrict__ csr_rw, const int* __restrict__ seid,
        const int* __restrict__ off,
        const float* __restrict__ W1, const float* __restrict__ b1,
        const float* __restrict__ W2,
        float* __restrict__ hn) {
    int wid = (blockIdx.x << 2) | (threadIdx.x >> 6);
    int lane = threadIdx.x & 63;
    if (wid >= N_NODES) return;
    int h = lane >> 5;            // which edge of the pair
    int c = lane & 31;            // float4 channel group: channels 4c..4c+3
    int s = off[wid], e = off[wid + 1];

    float4 acc = make_float4(0.f, 0.f, 0.f, 0.f);
    float ae = 0.f;
    const float4* yb = (const float4*)y1 + c;

    int t = s;
    for (; t + 3 < e; t += 4) {                    // 4 edges per iter, 2 chains
        float2 rw0 = csr_rw[t + h];
        float2 rw1 = csr_rw[t + 2 + h];
        int r0 = __float_as_int(rw0.x), r1 = __float_as_int(rw1.x);
        float4 y0 = yb[(size_t)r0 * 32];
        float4 y4 = yb[(size_t)r1 * 32];
        acc.x += y0.x * rw0.y; acc.y += y0.y * rw0.y;
        acc.z += y0.z * rw0.y; acc.w += y0.w * rw0.y;
        acc.x += y4.x * rw1.y; acc.y += y4.y * rw1.y;
        acc.z += y4.z * rw1.y; acc.w += y4.w * rw1.y;
        if (c < 16) {
            int id0 = seid[t + h], id1 = seid[t + 2 + h];
            ae += ea[(size_t)id0 * 16 + c] * rw0.y;
            ae += ea[(size_t)id1 * 16 + c] * rw1.y;
        }
    }
    for (; t < e; t += 2) {                        // remainder (guarded)
        int idx = t + h;
        bool valid = idx < e;
        int ic2 = valid ? idx : (e - 1);
        float2 rw = csr_rw[ic2];
        int r = __float_as_int(rw.x);
        float w = valid ? rw.y : 0.f;
        float4 y0 = yb[(size_t)r * 32];
        acc.x += y0.x * w; acc.y += y0.y * w;
        acc.z += y0.z * w; acc.w += y0.w * w;
        if (c < 16) {
            int id = seid[ic2];
            float ev = ea[(size_t)id * 16 + c];
            ae += valid ? ev * rw.y : 0.f;
        }
    }
    // combine the two halves
    acc.x += __shfl_xor(acc.x, 32, 64);
    acc.y += __shfl_xor(acc.y, 32, 64);
    acc.z += __shfl_xor(acc.z, 32, 64);
    acc.w += __shfl_xor(acc.w, 32, 64);
    ae += __shfl_xor(ae, 32, 64);

    float ic = 1.0f / fmaxf((float)(e - s), 1.0f);
    float4 b1v = *(const float4*)(b1 + c * 4);
    float4 o;
    o.x = acc.x * ic + b1v.x; o.y = acc.y * ic + b1v.y;
    o.z = acc.z * ic + b1v.z; o.w = acc.w * ic + b1v.w;
    ae *= ic;
    #pragma unroll
    for (int k = 0; k < 16; ++k) {                 // edge part @ W1[128+k,:]
        float sk = __shfl(ae, k, 64);
        float4 wv = *((const float4*)(W1 + (size_t)(128 + k) * 128) + c);
        o.x += sk * wv.x; o.y += sk * wv.y; o.z += sk * wv.z; o.w += sk * wv.w;
    }
    float ss    = o.x*o.x + o.y*o.y + o.z*o.z + o.w*o.w;
    float sspos = (o.x > 0.f ? o.x*o.x : 0.f) + (o.y > 0.f ? o.y*o.y : 0.f)
                + (o.z > 0.f ? o.z*o.z : 0.f) + (o.w > 0.f ? o.w*o.w : 0.f);
    ss = red32(ss);
    sspos = red32(sspos);
    float inv = rsqrtf(fmaxf(ss, 1e-24f));
    float4 h4;
    h4.x = fmaxf(o.x * inv, 0.f); h4.y = fmaxf(o.y * inv, 0.f);
    h4.z = fmaxf(o.z * inv, 0.f); h4.w = fmaxf(o.w * inv, 0.f);
    float nhv = sspos * inv * inv;                 // |relu(h)|^2
    // yh = relu(h) @ W2[0:128,:]
    float4 w0 = *(const float4*)(W2 + (size_t)(4*c + 0) * 4);
    float4 w1 = *(const float4*)(W2 + (size_t)(4*c + 1) * 4);
    float4 w2 = *(const float4*)(W2 + (size_t)(4*c + 2) * 4);
    float4 w3 = *(const float4*)(W2 + (size_t)(4*c + 3) * 4);
    float4 p;
    p.x = h4.x*w0.x + h4.y*w1.x + h4.z*w2.x + h4.w*w3.x;
    p.y = h4.x*w0.y + h4.y*w1.y + h4.z*w2.y + h4.w*w3.y;
    p.z = h4.x*w0.z + h4.y*w1.z + h4.z*w2.z + h4.w*w3.z;
    p.w = h4.x*w0.w + h4.y*w1.w + h4.z*w2.w + h4.w*w3.w;
    p.x = red32(p.x); p.y = red32(p.y); p.z = red32(p.z); p.w = red32(p.w);
    if (lane == 0) {
        *(float4*)(hn + (size_t)wid * 8) = p;
        hn[(size_t)wid * 8 + 4] = nhv;
    }
}

// ---- layer-2 c-pass (edge-parallel): c_e = w2 * (yh[row] + pea[e]) ----
__global__ __launch_bounds__(256) void cpass(
        const int* __restrict__ row, const float* __restrict__ hn,
        const float* __restrict__ sqea, const float4* __restrict__ pea,
        const int* __restrict__ epos, float4* __restrict__ cbuf) {
    int e = blockIdx.x * blockDim.x + threadIdx.x;
    if (e >= N_EDGES) return;
    int r = row[e];
    float4 yh4 = *(const float4*)(hn + (size_t)r * 8);
    float nhr = hn[(size_t)r * 8 + 4];
    float w2 = rsqrtf(fmaxf(nhr + sqea[e], 1e-24f));
    float4 pe = pea[e];
    float4 cv;
    cv.x = (yh4.x + pe.x) * w2; cv.y = (yh4.y + pe.y) * w2;
    cv.z = (yh4.z + pe.z) * w2; cv.w = (yh4.w + pe.w) * w2;
    cbuf[epos[e]] = cv;
}

// ---- layer-2 finish: mean over CSR range, +b2, normalize, sigmoid ----
__global__ __launch_bounds__(256) void layer2b(
        const float4* __restrict__ cbuf, const int* __restrict__ off,
        const float* __restrict__ b2, float* __restrict__ out) {
    int v = blockIdx.x * blockDim.x + threadIdx.x;
    if (v >= N_NODES) return;
    int s = off[v], e = off[v + 1];
    float4 a = make_float4(0.f, 0.f, 0.f, 0.f);
    for (int t = s; t < e; ++t) {
        float4 cv = cbuf[t];
        a.x += cv.x; a.y += cv.y; a.z += cv.z; a.w += cv.w;
    }
    float ic = 1.0f / fmaxf((float)(e - s), 1.0f);
    float4 o;
    o.x = a.x * ic + b2[0]; o.y = a.y * ic + b2[1];
    o.z = a.z * ic + b2[2]; o.w = a.w * ic + b2[3];
    float ss = o.x*o.x + o.y*o.y + o.z*o.z + o.w*o.w;
    float inv = rsqrtf(fmaxf(ss, 1e-24f));
    float4 res;
    res.x = 1.0f / (1.0f + expf(-(o.x * inv)));
    res.y = 1.0f / (1.0f + expf(-(o.y * inv)));
    res.z = 1.0f / (1.0f + expf(-(o.z * inv)));
    res.w = 1.0f / (1.0f + expf(-(o.w * inv)));
    *(float4*)(out + (size_t)v * 4) = res;
}

// ---------------- launch ----------------
extern "C" void kernel_launch(void* const* d_in, const int* in_sizes, int n_in,
                              void* d_out, int out_size, void* d_ws, size_t ws_size,
                              hipStream_t stream) {
    const float* x   = (const float*)d_in[0];
    const int*   ei  = (const int*)d_in[1];
    const float* ea  = (const float*)d_in[2];
    const float* W1  = (const float*)d_in[3];
    const float* b1  = (const float*)d_in[4];
    const float* W2  = (const float*)d_in[5];
    const float* b2  = (const float*)d_in[6];
    const int* row = ei;
    const int* col = ei + N_EDGES;
    float* out = (float*)d_out;

    char* ws = (char*)d_ws;
    size_t o = 0;
    auto carve = [&](size_t bytes) { char* p = ws + o; o = (o + bytes + 255) & ~(size_t)255; return p; };
    float*  y1     = (float*)carve((size_t)N_NODES * 128 * 4);   // 51.2 MB
    float*  sqea   = (float*)carve((size_t)N_EDGES * 4);         // 6.4 MB
    float2* csr_rw = (float2*)carve((size_t)N_EDGES * 8);        // 12.8 MB
    int*    seid   = (int*)carve((size_t)N_EDGES * 4);           // 6.4 MB
    int*    epos   = (int*)carve((size_t)N_EDGES * 4);           // 6.4 MB
    float4* pea    = (float4*)carve((size_t)N_EDGES * 16);       // 25.6 MB
    float4* cbuf   = (float4*)carve((size_t)N_EDGES * 16);       // 25.6 MB
    int*    cnt    = (int*)carve((size_t)N_NODES * 4);
    int*    off    = (int*)carve((size_t)(N_NODES + 1) * 4);
    int*    head   = (int*)carve((size_t)N_NODES * 4);
    float*  nx     = (float*)carve((size_t)N_NODES * 4);
    float*  hn     = (float*)carve((size_t)N_NODES * 8 * 4);     // {yh4, nh, pad3}
    int*    psum   = (int*)carve((size_t)NCHUNKS * 4);
    int*    coff   = (int*)carve((size_t)NCHUNKS * 4);
    (void)ws_size; (void)in_sizes; (void)n_in; (void)out_size;

    hipMemsetAsync(cnt, 0, (size_t)N_NODES * 4, stream);

    dim3 b256(256);
    prep_edges<<<(N_EDGES + 255) / 256, b256, 0, stream>>>(ea, col, W2, sqea, pea, cnt);
    node_sq<<<(N_NODES + 255) / 256, b256, 0, stream>>>(x, nx);
    gemm_y1<<<(N_NODES + 63) / 64, b256, 0, stream>>>(x, W1, y1);

    scan_part<<<NCHUNKS, CHUNK, 0, stream>>>(cnt, psum);
    scan_top<<<1, 64, 0, stream>>>(psum, coff, off);
    scan_apply<<<NCHUNKS, CHUNK, 0, stream>>>(cnt, coff, off, head);
    scatter_e<<<(N_EDGES + 255) / 256, b256, 0, stream>>>(row, col, nx, sqea, head,
                                                          csr_rw, seid, epos);

    layer1<<<(N_NODES + 3) / 4, b256, 0, stream>>>(y1, ea, csr_rw, seid, off,
                                                   W1, b1, W2, hn);
    cpass<<<(N_EDGES + 255) / 256, b256, 0, stream>>>(row, hn, sqea, pea, epos, cbuf);
    layer2b<<<(N_NODES + 255) / 256, b256, 0, stream>>>(cbuf, off, b2, out);
}

// Round 3
// 432.121 us; speedup vs baseline: 1.4663x; 1.1602x over previous
//
#include <hip/hip_runtime.h>
#include <hip/hip_fp16.h>
#include <math.h>

#define N_NODES 100000
#define N_EDGES 1600000
#define CHUNK 1024
#define NCHUNKS ((N_NODES + CHUNK - 1) / CHUNK)   // 98

union H4 { uint2 u; __half2 h[2]; };

__device__ __forceinline__ float red32(float v) {
    #pragma unroll
    for (int m = 16; m >= 1; m >>= 1) v += __shfl_xor(v, m, 64);
    return v;
}

// ---------- kernel 1: per-edge |ea|^2, pea = ea@W2e, degree histogram ----------
__global__ __launch_bounds__(256) void prep_edges(
        const float* __restrict__ ea, const int* __restrict__ col,
        const float* __restrict__ W2,
        float* __restrict__ sqea, float4* __restrict__ pea, int* __restrict__ cnt) {
    __shared__ float w2e[64];                 // W2[128:144, 0:4]
    int t = threadIdx.x;
    if (t < 64) w2e[t] = W2[128 * 4 + t];
    __syncthreads();
    int e = blockIdx.x * 256 + t;
    if (e >= N_EDGES) return;
    const float4* p = (const float4*)(ea + (size_t)e * 16);
    float4 q0 = p[0], q1 = p[1], q2 = p[2], q3 = p[3];
    float a[16] = {q0.x,q0.y,q0.z,q0.w, q1.x,q1.y,q1.z,q1.w,
                   q2.x,q2.y,q2.z,q2.w, q3.x,q3.y,q3.z,q3.w};
    float s = 0.f;
    float4 pv = make_float4(0.f, 0.f, 0.f, 0.f);
    #pragma unroll
    for (int k = 0; k < 16; ++k) {
        s += a[k] * a[k];
        pv.x += a[k] * w2e[k * 4 + 0];
        pv.y += a[k] * w2e[k * 4 + 1];
        pv.z += a[k] * w2e[k * 4 + 2];
        pv.w += a[k] * w2e[k * 4 + 3];
    }
    sqea[e] = s;
    pea[e] = pv;
    atomicAdd(&cnt[col[e]], 1);
}

// ---------------- scan (3 kernels) ----------------
__global__ void scan_part(const int* __restrict__ cnt, int* __restrict__ psum) {
    __shared__ int sd[CHUNK];
    int i = blockIdx.x * CHUNK + threadIdx.x;
    sd[threadIdx.x] = (i < N_NODES) ? cnt[i] : 0;
    __syncthreads();
    for (int s = CHUNK / 2; s > 0; s >>= 1) {
        if (threadIdx.x < s) sd[threadIdx.x] += sd[threadIdx.x + s];
        __syncthreads();
    }
    if (threadIdx.x == 0) psum[blockIdx.x] = sd[0];
}

__global__ void scan_top(const int* __restrict__ psum, int* __restrict__ coff,
                         int* __restrict__ off) {
    if (blockIdx.x == 0 && threadIdx.x == 0) {
        int run = 0;
        for (int i = 0; i < NCHUNKS; ++i) { coff[i] = run; run += psum[i]; }
        off[N_NODES] = N_EDGES;
    }
}

__global__ void scan_apply(const int* __restrict__ cnt, const int* __restrict__ coff,
                           int* __restrict__ off, int* __restrict__ head) {
    __shared__ int sd[CHUNK];
    int i = blockIdx.x * CHUNK + threadIdx.x;
    int v = (i < N_NODES) ? cnt[i] : 0;
    sd[threadIdx.x] = v;
    __syncthreads();
    for (int s = 1; s < CHUNK; s <<= 1) {
        int t = (threadIdx.x >= s) ? sd[threadIdx.x - s] : 0;
        __syncthreads();
        sd[threadIdx.x] += t;
        __syncthreads();
    }
    if (i < N_NODES) {
        int excl = coff[blockIdx.x] + sd[threadIdx.x] - v;
        off[i] = excl;
        head[i] = excl;
    }
}

// ---- scatter edges into CSR-by-col; meta = {row, w1_bits, eid, 0} ----
__global__ __launch_bounds__(256) void scatter_e(
        const int* __restrict__ row, const int* __restrict__ col,
        const float* __restrict__ nx, const float* __restrict__ sqea,
        int* __restrict__ head, int4* __restrict__ csr4, int* __restrict__ epos) {
    int e = blockIdx.x * blockDim.x + threadIdx.x;
    if (e >= N_EDGES) return;
    int c = col[e];
    int r = row[e];
    float w1 = rsqrtf(fmaxf(nx[r] + sqea[e], 1e-24f));  // == 1/max(sqrt(s),1e-12)
    int p = atomicAdd(&head[c], 1);
    int4 mt; mt.x = r; mt.y = __float_as_int(w1); mt.z = e; mt.w = 0;
    csr4[p] = mt;
    epos[e] = p;
}

// ---- y1h = half(x @ W1[0:128,:])  + nx = |x|^2 fused ----
__global__ __launch_bounds__(256) void gemm_y1h(const float* __restrict__ x,
                                                const float* __restrict__ W1,
                                                __half* __restrict__ y1h,
                                                float* __restrict__ nx) {
    __shared__ float xs[64][129];
    int r0 = blockIdx.x * 64;
    int t = threadIdx.x;
    for (int i = t; i < 64 * 32; i += 256) {
        int rr = i >> 5, c4 = (i & 31) * 4;
        int gr = r0 + rr;
        float4 v = (gr < N_NODES) ? *(const float4*)(x + (size_t)gr * 128 + c4)
                                  : make_float4(0.f, 0.f, 0.f, 0.f);
        xs[rr][c4] = v.x; xs[rr][c4 + 1] = v.y; xs[rr][c4 + 2] = v.z; xs[rr][c4 + 3] = v.w;
    }
    __syncthreads();
    // fused |x|^2: thread t handles row t>>2, quarter t&3
    {
        int rr = t >> 2, q = t & 3;
        float s = 0.f;
        #pragma unroll
        for (int k = 0; k < 32; ++k) { float v = xs[rr][q * 32 + k]; s += v * v; }
        s += __shfl_xor(s, 1, 64);
        s += __shfl_xor(s, 2, 64);
        if (q == 0 && r0 + rr < N_NODES) nx[r0 + rr] = s;
    }
    int tx = t & 31, ty = t >> 5;
    float4 acc[8];
    #pragma unroll
    for (int i = 0; i < 8; ++i) acc[i] = make_float4(0.f, 0.f, 0.f, 0.f);
    for (int k = 0; k < 128; ++k) {
        float4 wv = *(const float4*)(W1 + (size_t)k * 128 + tx * 4);
        #pragma unroll
        for (int i = 0; i < 8; ++i) {
            float xv = xs[ty * 8 + i][k];
            acc[i].x += xv * wv.x; acc[i].y += xv * wv.y;
            acc[i].z += xv * wv.z; acc[i].w += xv * wv.w;
        }
    }
    #pragma unroll
    for (int i = 0; i < 8; ++i) {
        int rr = r0 + ty * 8 + i;
        if (rr < N_NODES) {
            H4 pk;
            pk.h[0] = __float22half2_rn(make_float2(acc[i].x, acc[i].y));
            pk.h[1] = __float22half2_rn(make_float2(acc[i].z, acc[i].w));
            *(uint2*)(y1h + (size_t)rr * 128 + tx * 4) = pk.u;
        }
    }
}

// ---- layer-1: wave/node, reg-preloaded CSR meta, fp16 gathers, 8 edges/iter ----
__global__ __launch_bounds__(256) void layer1(
        const __half* __restrict__ y1h, const float* __restrict__ ea,
        const int4* __restrict__ csr4, const int* __restrict__ off,
        const float* __restrict__ W1, const float* __restrict__ b1,
        const float* __restrict__ W2,
        float* __restrict__ hn) {
    int wid = (blockIdx.x << 2) | (threadIdx.x >> 6);
    int lane = threadIdx.x & 63;
    if (wid >= N_NODES) return;
    int h = lane >> 5;            // which edge of the pair
    int c = lane & 31;            // channels 4c..4c+3
    int s = off[wid], e = off[wid + 1];
    int deg = e - s;
    int m = (deg < 64) ? deg : 64;
    int4 meta = (lane < m) ? csr4[s + lane] : make_int4(0, 0, 0, 0);

    float4 acc = make_float4(0.f, 0.f, 0.f, 0.f);
    float4 ae4 = make_float4(0.f, 0.f, 0.f, 0.f);

    int j = 0;
    for (; j + 8 <= m; j += 8) {                 // 8 edges per iter, 4 indep gathers
        #pragma unroll
        for (int i = 0; i < 4; ++i) {
            int idx = j + 2 * i + h;
            int r   = __shfl(meta.x, idx, 64);
            float w = __int_as_float(__shfl(meta.y, idx, 64));
            int id  = __shfl(meta.z, idx, 64);
            H4 pk; pk.u = *(const uint2*)(y1h + (size_t)r * 128 + c * 4);
            float2 f0 = __half22float2(pk.h[0]);
            float2 f1 = __half22float2(pk.h[1]);
            acc.x += f0.x * w; acc.y += f0.y * w;
            acc.z += f1.x * w; acc.w += f1.y * w;
            if (c < 4) {
                float4 ev = *(const float4*)(ea + (size_t)id * 16 + c * 4);
                ae4.x += ev.x * w; ae4.y += ev.y * w;
                ae4.z += ev.z * w; ae4.w += ev.w * w;
            }
        }
    }
    for (; j < m; j += 2) {                      // remainder, masked
        int idx = j + h;
        bool val = idx < m;
        int ii = val ? idx : 0;
        int r   = __shfl(meta.x, ii, 64);
        float w = val ? __int_as_float(__shfl(meta.y, ii, 64)) : 0.f;
        int id  = __shfl(meta.z, ii, 64);
        H4 pk; pk.u = *(const uint2*)(y1h + (size_t)r * 128 + c * 4);
        float2 f0 = __half22float2(pk.h[0]);
        float2 f1 = __half22float2(pk.h[1]);
        acc.x += f0.x * w; acc.y += f0.y * w;
        acc.z += f1.x * w; acc.w += f1.y * w;
        if (c < 4) {
            float4 ev = *(const float4*)(ea + (size_t)id * 16 + c * 4);
            ae4.x += ev.x * w; ae4.y += ev.y * w;
            ae4.z += ev.z * w; ae4.w += ev.w * w;
        }
    }
    if (deg > 64) {                              // essentially-never fallback
        for (int j2 = 64; j2 < deg; j2 += 2) {
            int idx = j2 + h;
            bool val = idx < deg;
            int4 mt = csr4[s + (val ? idx : deg - 1)];
            int r = mt.x;
            float w = val ? __int_as_float(mt.y) : 0.f;
            int id = mt.z;
            H4 pk; pk.u = *(const uint2*)(y1h + (size_t)r * 128 + c * 4);
            float2 f0 = __half22float2(pk.h[0]);
            float2 f1 = __half22float2(pk.h[1]);
            acc.x += f0.x * w; acc.y += f0.y * w;
            acc.z += f1.x * w; acc.w += f1.y * w;
            if (c < 4) {
                float4 ev = *(const float4*)(ea + (size_t)id * 16 + c * 4);
                ae4.x += ev.x * w; ae4.y += ev.y * w;
                ae4.z += ev.z * w; ae4.w += ev.w * w;
            }
        }
    }
    // combine the two halves
    acc.x += __shfl_xor(acc.x, 32, 64);
    acc.y += __shfl_xor(acc.y, 32, 64);
    acc.z += __shfl_xor(acc.z, 32, 64);
    acc.w += __shfl_xor(acc.w, 32, 64);
    ae4.x += __shfl_xor(ae4.x, 32, 64);
    ae4.y += __shfl_xor(ae4.y, 32, 64);
    ae4.z += __shfl_xor(ae4.z, 32, 64);
    ae4.w += __shfl_xor(ae4.w, 32, 64);

    float ic = 1.0f / fmaxf((float)deg, 1.0f);
    float4 b1v = *(const float4*)(b1 + c * 4);
    float4 o;
    o.x = acc.x * ic + b1v.x; o.y = acc.y * ic + b1v.y;
    o.z = acc.z * ic + b1v.z; o.w = acc.w * ic + b1v.w;
    ae4.x *= ic; ae4.y *= ic; ae4.z *= ic; ae4.w *= ic;
    float aev[4] = {ae4.x, ae4.y, ae4.z, ae4.w};
    #pragma unroll
    for (int k = 0; k < 16; ++k) {               // edge part @ W1[128+k,:]
        float sk = __shfl(aev[k & 3], k >> 2, 64);   // channel k lives in lane k>>2
        float4 wv = *((const float4*)(W1 + (size_t)(128 + k) * 128) + c);
        o.x += sk * wv.x; o.y += sk * wv.y; o.z += sk * wv.z; o.w += sk * wv.w;
    }
    float ss    = o.x*o.x + o.y*o.y + o.z*o.z + o.w*o.w;
    float sspos = (o.x > 0.f ? o.x*o.x : 0.f) + (o.y > 0.f ? o.y*o.y : 0.f)
                + (o.z > 0.f ? o.z*o.z : 0.f) + (o.w > 0.f ? o.w*o.w : 0.f);
    ss = red32(ss);
    sspos = red32(sspos);
    float inv = rsqrtf(fmaxf(ss, 1e-24f));
    float4 h4;
    h4.x = fmaxf(o.x * inv, 0.f); h4.y = fmaxf(o.y * inv, 0.f);
    h4.z = fmaxf(o.z * inv, 0.f); h4.w = fmaxf(o.w * inv, 0.f);
    float nhv = sspos * inv * inv;               // |relu(h)|^2
    // yh = relu(h) @ W2[0:128,:]
    float4 w0 = *(const float4*)(W2 + (size_t)(4*c + 0) * 4);
    float4 w1 = *(const float4*)(W2 + (size_t)(4*c + 1) * 4);
    float4 w2 = *(const float4*)(W2 + (size_t)(4*c + 2) * 4);
    float4 w3 = *(const float4*)(W2 + (size_t)(4*c + 3) * 4);
    float4 p;
    p.x = h4.x*w0.x + h4.y*w1.x + h4.z*w2.x + h4.w*w3.x;
    p.y = h4.x*w0.y + h4.y*w1.y + h4.z*w2.y + h4.w*w3.y;
    p.z = h4.x*w0.z + h4.y*w1.z + h4.z*w2.z + h4.w*w3.z;
    p.w = h4.x*w0.w + h4.y*w1.w + h4.z*w2.w + h4.w*w3.w;
    p.x = red32(p.x); p.y = red32(p.y); p.z = red32(p.z); p.w = red32(p.w);
    if (lane == 0) {
        *(float4*)(hn + (size_t)wid * 8) = p;
        hn[(size_t)wid * 8 + 4] = nhv;
    }
}

// ---- layer-2 c-pass (edge-parallel): c_e = w2 * (yh[row] + pea[e]) ----
__global__ __launch_bounds__(256) void cpass(
        const int* __restrict__ row, const float* __restrict__ hn,
        const float* __restrict__ sqea, const float4* __restrict__ pea,
        const int* __restrict__ epos, float4* __restrict__ cbuf) {
    int e = blockIdx.x * blockDim.x + threadIdx.x;
    if (e >= N_EDGES) return;
    int r = row[e];
    float4 yh4 = *(const float4*)(hn + (size_t)r * 8);
    float nhr = hn[(size_t)r * 8 + 4];
    float w2 = rsqrtf(fmaxf(nhr + sqea[e], 1e-24f));
    float4 pe = pea[e];
    float4 cv;
    cv.x = (yh4.x + pe.x) * w2; cv.y = (yh4.y + pe.y) * w2;
    cv.z = (yh4.z + pe.z) * w2; cv.w = (yh4.w + pe.w) * w2;
    cbuf[epos[e]] = cv;
}

// ---- layer-2 finish: mean over CSR range, +b2, normalize, sigmoid ----
__global__ __launch_bounds__(256) void layer2b(
        const float4* __restrict__ cbuf, const int* __restrict__ off,
        const float* __restrict__ b2, float* __restrict__ out) {
    int v = blockIdx.x * blockDim.x + threadIdx.x;
    if (v >= N_NODES) return;
    int s = off[v], e = off[v + 1];
    float4 a = make_float4(0.f, 0.f, 0.f, 0.f);
    for (int t = s; t < e; ++t) {
        float4 cv = cbuf[t];
        a.x += cv.x; a.y += cv.y; a.z += cv.z; a.w += cv.w;
    }
    float ic = 1.0f / fmaxf((float)(e - s), 1.0f);
    float4 o;
    o.x = a.x * ic + b2[0]; o.y = a.y * ic + b2[1];
    o.z = a.z * ic + b2[2]; o.w = a.w * ic + b2[3];
    float ss = o.x*o.x + o.y*o.y + o.z*o.z + o.w*o.w;
    float inv = rsqrtf(fmaxf(ss, 1e-24f));
    float4 res;
    res.x = 1.0f / (1.0f + expf(-(o.x * inv)));
    res.y = 1.0f / (1.0f + expf(-(o.y * inv)));
    res.z = 1.0f / (1.0f + expf(-(o.z * inv)));
    res.w = 1.0f / (1.0f + expf(-(o.w * inv)));
    *(float4*)(out + (size_t)v * 4) = res;
}

// ---------------- launch ----------------
extern "C" void kernel_launch(void* const* d_in, const int* in_sizes, int n_in,
                              void* d_out, int out_size, void* d_ws, size_t ws_size,
                              hipStream_t stream) {
    const float* x   = (const float*)d_in[0];
    const int*   ei  = (const int*)d_in[1];
    const float* ea  = (const float*)d_in[2];
    const float* W1  = (const float*)d_in[3];
    const float* b1  = (const float*)d_in[4];
    const float* W2  = (const float*)d_in[5];
    const float* b2  = (const float*)d_in[6];
    const int* row = ei;
    const int* col = ei + N_EDGES;
    float* out = (float*)d_out;

    char* ws = (char*)d_ws;
    size_t o = 0;
    auto carve = [&](size_t bytes) { char* p = ws + o; o = (o + bytes + 255) & ~(size_t)255; return p; };
    __half* y1h    = (__half*)carve((size_t)N_NODES * 128 * 2);  // 25.6 MB
    float*  sqea   = (float*)carve((size_t)N_EDGES * 4);         // 6.4 MB
    int4*   csr4   = (int4*)carve((size_t)N_EDGES * 16);         // 25.6 MB
    int*    epos   = (int*)carve((size_t)N_EDGES * 4);           // 6.4 MB
    float4* pea    = (float4*)carve((size_t)N_EDGES * 16);       // 25.6 MB
    float4* cbuf   = (float4*)carve((size_t)N_EDGES * 16);       // 25.6 MB
    int*    cnt    = (int*)carve((size_t)N_NODES * 4);
    int*    off    = (int*)carve((size_t)(N_NODES + 1) * 4);
    int*    head   = (int*)carve((size_t)N_NODES * 4);
    float*  nx     = (float*)carve((size_t)N_NODES * 4);
    float*  hn     = (float*)carve((size_t)N_NODES * 8 * 4);     // {yh4, nh, pad3}
    int*    psum   = (int*)carve((size_t)NCHUNKS * 4);
    int*    coff   = (int*)carve((size_t)NCHUNKS * 4);
    (void)ws_size; (void)in_sizes; (void)n_in; (void)out_size;

    hipMemsetAsync(cnt, 0, (size_t)N_NODES * 4, stream);

    dim3 b256(256);
    prep_edges<<<(N_EDGES + 255) / 256, b256, 0, stream>>>(ea, col, W2, sqea, pea, cnt);
    gemm_y1h<<<(N_NODES + 63) / 64, b256, 0, stream>>>(x, W1, y1h, nx);

    scan_part<<<NCHUNKS, CHUNK, 0, stream>>>(cnt, psum);
    scan_top<<<1, 64, 0, stream>>>(psum, coff, off);
    scan_apply<<<NCHUNKS, CHUNK, 0, stream>>>(cnt, coff, off, head);
    scatter_e<<<(N_EDGES + 255) / 256, b256, 0, stream>>>(row, col, nx, sqea, head,
                                                          csr4, epos);

    layer1<<<(N_NODES + 3) / 4, b256, 0, stream>>>(y1h, ea, csr4, off, W1, b1, W2, hn);
    cpass<<<(N_EDGES + 255) / 256, b256, 0, stream>>>(row, hn, sqea, pea, epos, cbuf);
    layer2b<<<(N_NODES + 255) / 256, b256, 0, stream>>>(cbuf, off, b2, out);
}